// Round 13
// baseline (655.195 us; speedup 1.0000x reference)
//
#include <hip/hip_runtime.h>

#define TT 1500
#define BB 96
#define VV 128
#define LGT 256
#define LCAP 512
#define NEGF (-1.0e30f)
#define L2E 1.4426950408889634f
#define LN2F 0.6931471805599453f
#define HREF 30  // 2*HREF=60 < 62-state ghost
#define NW 16    // waves per CTC block

// ---------------------------------------------------------------------------
// Kernel 1: greedy decode (unchanged).
// ---------------------------------------------------------------------------
__global__ __launch_bounds__(256) void decode_kernel(
    const float* __restrict__ acts, const int* __restrict__ act_lens,
    int* __restrict__ dec, int* __restrict__ dec_lens) {
  __shared__ int preds[TT];
  __shared__ int sc[256];
  const int b = blockIdx.x;
  const int tid = threadIdx.x;
  const int Tl = act_lens[b];
  for (int t = tid; t < Tl; t += 256) {
    const float4* r4 = (const float4*)(acts + ((size_t)t * BB + b) * VV);
    float best = -3.4e38f;
    int bi = 0;
#pragma unroll
    for (int i = 0; i < VV / 4; i++) {
      float4 v = r4[i];
      if (v.x > best) { best = v.x; bi = 4 * i; }
      if (v.y > best) { best = v.y; bi = 4 * i + 1; }
      if (v.z > best) { best = v.z; bi = 4 * i + 2; }
      if (v.w > best) { best = v.w; bi = 4 * i + 3; }
    }
    preds[t] = bi;
  }
  __syncthreads();

  int pv[6];
  bool fl[6];
  int cnt = 0;
#pragma unroll
  for (int j = 0; j < 6; j++) {
    int t = tid * 6 + j;
    bool valid = t < Tl;
    int p = valid ? preds[t] : 0;
    int pr = (t == 0) ? -1 : (valid ? preds[t - 1] : -1);
    bool f = valid && (p != 0) && (p != pr);
    pv[j] = p;
    fl[j] = f;
    cnt += f;
  }
  sc[tid] = cnt;
  __syncthreads();
  for (int off = 1; off < 256; off <<= 1) {
    int v = sc[tid];
    if (tid >= off) v += sc[tid - off];
    __syncthreads();
    sc[tid] = v;
    __syncthreads();
  }
  int pos = sc[tid] - cnt;  // exclusive prefix
  int total = sc[255];
  int* db = dec + (size_t)b * LCAP;
#pragma unroll
  for (int j = 0; j < 6; j++) {
    if (fl[j]) {
      if (pos < LCAP) db[pos] = pv[j];
      pos++;
    }
  }
  if (tid == 0) {
    if (total == 0) db[0] = 0;
    dec_lens[b] = max(1, min(total, LCAP));
  }
}

// ---------------------------------------------------------------------------
// Kernel 2: CTC on raw acts, LOG2 domain, 16 waves, R=2 even/odd layout
// (r12 structure, passed absmax 4.0). SINGLE CHANGE vs r12: the per-step
// cross-lane rotate uses DPP wave_shr:1 (VALU pipe, ~4cy) instead of
// ds_bpermute (~120cy LDS round-trip on the recurrence chain); lane 0 gets
// NEGF via the DPP 'old' operand (cndmask deleted too).
// ---------------------------------------------------------------------------
__device__ __forceinline__ float shr1_negf(float x) {
  // lane i <- lane i-1's x; lane 0 <- NEGF.  DPP ctrl 0x138 = wave_shr:1.
  int r = __builtin_amdgcn_update_dpp(__float_as_int(NEGF), __float_as_int(x),
                                      0x138, 0xf, 0xf, false);
  return __int_as_float(r);
}

__global__ __launch_bounds__(1024, 1) void ctc_kernel(
    const float* __restrict__ acts, const int* __restrict__ labels_gt,
    const int* __restrict__ act_lens, const int* __restrict__ label_lens,
    const int* __restrict__ dec, const int* __restrict__ dec_lens,
    float* __restrict__ ends) {
  __shared__ float xall[2 * LCAP + 2];
  __shared__ float fin[2];
  const int b = blockIdx.x >> 1;
  const int hyp = blockIdx.x & 1;
  const int Tl = act_lens[b];
  const int len = hyp ? dec_lens[b] : label_lens[b];
  const int* lab = hyp ? (dec + (size_t)b * LCAP) : (labels_gt + (size_t)b * LGT);
  const int S = 2 * len + 1;
  const float* act_b = acts + (size_t)b * VV;  // acts[(t*BB + b)*VV + v]

  const int tid = threadIdx.x;
  const int lane = tid & 63, wv = tid >> 6;
  const int oS = 2 * ((S + 2 * NW - 1) / (2 * NW));  // even owned span
  const int Se = (S + 1) & ~1;
  const int o0 = min(wv * oS, Se);            // even
  const int o1 = min(o0 + oS, S);
  const int p0 = max(0, o0 - 62);             // even ghost bottom
  const int s0 = p0 + 2 * lane;               // blank state (even)
  const int s1 = s0 + 1;                      // label state (odd)

  int e1 = 0;
  bool skip = false;
  if (s1 < S) {
    int li = s1 >> 1;
    e1 = lab[li];
    if (s1 >= 3) skip = (e1 != 0) && (e1 != lab[li - 1]);
  }

  float a0 = NEGF, a1 = NEGF;
  if (wv == 0 && lane == 0) {
    a0 = act_b[0] * L2E;
    a1 = act_b[e1] * L2E;  // S >= 3 always (len >= 1)
  }

  float gL0, gL1, gL2, gL3;  // label logits (divergent gather)
  float gB0, gB1, gB2, gB3;  // blank logits (wave-uniform)

#define PREF(GL, GB, ROW)                                  \
  {                                                        \
    const float* rp_ = act_b + (size_t)(ROW) * (BB * VV);  \
    GB = rp_[0];                                           \
    GL = rp_[e1];                                          \
  }

#define STEPK(GL, GB)                                                     \
  {                                                                       \
    float pe = shr1_negf(a1);                                             \
    /* blank (even): lse2(a0, pe) + GB */                                 \
    float m0 = fmaxf(a0, pe);                                             \
    float d0 = fminf(a0, pe) - m0;                                        \
    float n0 = m0 + __builtin_log2f(1.0f + __builtin_exp2f(d0));          \
    /* label (odd): lse3(a1, a0_old, skip?pe:NEG) + GL */                 \
    float c2 = skip ? pe : NEGF;                                          \
    float m1 = fmaxf(fmaxf(a1, a0), c2);                                  \
    float dm = __builtin_amdgcn_fmed3f(a1, a0, c2) - m1;                  \
    float dn = fminf(fminf(a1, a0), c2) - m1;                             \
    float n1 = m1 + __builtin_log2f(1.0f + __builtin_exp2f(dm) +          \
                                    __builtin_exp2f(dn));                 \
    a0 = __builtin_fmaf(GB, L2E, n0);                                     \
    a1 = __builtin_fmaf(GL, L2E, n1);                                     \
  }

#define REFRESH()                                        \
  {                                                      \
    __syncthreads();                                     \
    if (s0 >= o0 && s0 < o1) xall[s0] = a0;              \
    if (s1 >= o0 && s1 < o1) xall[s1] = a1;              \
    __syncthreads();                                     \
    if (s0 < o0) {                                       \
      a0 = xall[s0];                                     \
      a1 = (s1 < S) ? xall[s1] : NEGF;                   \
    }                                                    \
  }

#define STAGE(UL, UB, PL, PB)              \
  STEPK(UL, UB);                           \
  PREF(PL, PB, min(t + 3, Tl - 1));        \
  ++t;                                     \
  if (++since >= HREF) {                   \
    if (t < Tl) REFRESH();                 \
    since = 0;                             \
  }                                        \
  if (t >= Tl) break;

  PREF(gL1, gB1, min(1, Tl - 1));
  PREF(gL2, gB2, min(2, Tl - 1));
  PREF(gL3, gB3, min(3, Tl - 1));

  int t = 1, since = 0;
  while (t < Tl) {
    STAGE(gL1, gB1, gL0, gB0)
    STAGE(gL2, gB2, gL1, gB1)
    STAGE(gL3, gB3, gL2, gB2)
    STAGE(gL0, gB0, gL3, gB3)
  }
#undef STAGE
#undef REFRESH
#undef STEPK
#undef PREF

  // end = logaddexp(al[2*len], al[2*len-1]) from owned states
  if (s0 >= o0 && s0 < o1 && s0 == 2 * len) fin[0] = a0;
  if (s1 >= o0 && s1 < o1 && s1 == 2 * len - 1) fin[1] = a1;
  __syncthreads();
  if (tid == 0) {
    float a = fin[0], c = fin[1];
    float m = fmaxf(a, c);
    float e = m + __builtin_log2f(__builtin_exp2f(a - m) + __builtin_exp2f(c - m));
    ends[hyp * BB + b] = e;
  }
}

// ---------------------------------------------------------------------------
// Kernel 3: out[b] = (end_hyp' - end_gt') * ln2 + 1.0  (log2-domain ends)
// ---------------------------------------------------------------------------
__global__ void final_kernel(const float* __restrict__ ends,
                             float* __restrict__ out) {
  int b = threadIdx.x;
  if (b < BB) out[b] = (ends[BB + b] - ends[b]) * LN2F + 1.0f;
}

extern "C" void kernel_launch(void* const* d_in, const int* in_sizes, int n_in,
                              void* d_out, int out_size, void* d_ws,
                              size_t ws_size, hipStream_t stream) {
  const float* acts = (const float*)d_in[0];
  const int* labels = (const int*)d_in[1];
  const int* act_lens = (const int*)d_in[2];
  const int* label_lens = (const int*)d_in[3];
  float* out = (float*)d_out;

  char* ws = (char*)d_ws;
  int* dec = (int*)ws;                                          // B*LCAP ints
  int* dec_lens = (int*)(ws + (size_t)BB * LCAP * 4);           // B ints
  float* ends = (float*)(ws + (size_t)BB * LCAP * 4 + BB * 4);  // 2*B floats

  decode_kernel<<<dim3(BB), dim3(256), 0, stream>>>(acts, act_lens, dec, dec_lens);
  ctc_kernel<<<dim3(2 * BB), dim3(1024), 0, stream>>>(
      acts, labels, act_lens, label_lens, dec, dec_lens, ends);
  final_kernel<<<dim3(1), dim3(128), 0, stream>>>(ends, out);
}

// Round 14
// 547.163 us; speedup vs baseline: 1.1974x; 1.1974x over previous
//
#include <hip/hip_runtime.h>

#define TT 1500
#define BB 96
#define VV 128
#define LGT 256
#define LCAP 512
#define NEGF (-1.0e30f)
#define L2E 1.4426950408889634f
#define LN2F 0.6931471805599453f
#define NW 16  // waves per CTC block

// ---------------------------------------------------------------------------
// Kernel 1: greedy decode (unchanged).
// ---------------------------------------------------------------------------
__global__ __launch_bounds__(256) void decode_kernel(
    const float* __restrict__ acts, const int* __restrict__ act_lens,
    int* __restrict__ dec, int* __restrict__ dec_lens) {
  __shared__ int preds[TT];
  __shared__ int sc[256];
  const int b = blockIdx.x;
  const int tid = threadIdx.x;
  const int Tl = act_lens[b];
  for (int t = tid; t < Tl; t += 256) {
    const float4* r4 = (const float4*)(acts + ((size_t)t * BB + b) * VV);
    float best = -3.4e38f;
    int bi = 0;
#pragma unroll
    for (int i = 0; i < VV / 4; i++) {
      float4 v = r4[i];
      if (v.x > best) { best = v.x; bi = 4 * i; }
      if (v.y > best) { best = v.y; bi = 4 * i + 1; }
      if (v.z > best) { best = v.z; bi = 4 * i + 2; }
      if (v.w > best) { best = v.w; bi = 4 * i + 3; }
    }
    preds[t] = bi;
  }
  __syncthreads();

  int pv[6];
  bool fl[6];
  int cnt = 0;
#pragma unroll
  for (int j = 0; j < 6; j++) {
    int t = tid * 6 + j;
    bool valid = t < Tl;
    int p = valid ? preds[t] : 0;
    int pr = (t == 0) ? -1 : (valid ? preds[t - 1] : -1);
    bool f = valid && (p != 0) && (p != pr);
    pv[j] = p;
    fl[j] = f;
    cnt += f;
  }
  sc[tid] = cnt;
  __syncthreads();
  for (int off = 1; off < 256; off <<= 1) {
    int v = sc[tid];
    if (tid >= off) v += sc[tid - off];
    __syncthreads();
    sc[tid] = v;
    __syncthreads();
  }
  int pos = sc[tid] - cnt;  // exclusive prefix
  int total = sc[255];
  int* db = dec + (size_t)b * LCAP;
#pragma unroll
  for (int j = 0; j < 6; j++) {
    if (fl[j]) {
      if (pos < LCAP) db[pos] = pv[j];
      pos++;
    }
  }
  if (tid == 0) {
    if (total == 0) db[0] = 0;
    dec_lens[b] = max(1, min(total, LCAP));
  }
}

// ---------------------------------------------------------------------------
// Kernel 2: CTC, r12/r13 structure and math (absmax 4.0), restructured
// schedule: BRANCH-FREE 30-step windows (one straight-line BB; 30 unrolled
// STEP+PREF pairs, no breaks/refresh checks inside) + prefetch depth 6
// (12 loads in flight, SALU-clamped row index). REFRESH once per window
// (2*30=60 < 62-state ghost). Branchy 6-phase tail handles the remainder.
// ---------------------------------------------------------------------------
__device__ __forceinline__ float shr1_negf(float x) {
  // lane i <- lane i-1's x; lane 0 <- NEGF.  DPP ctrl 0x138 = wave_shr:1.
  int r = __builtin_amdgcn_update_dpp(__float_as_int(NEGF), __float_as_int(x),
                                      0x138, 0xf, 0xf, false);
  return __int_as_float(r);
}

__global__ __launch_bounds__(1024, 1) void ctc_kernel(
    const float* __restrict__ acts, const int* __restrict__ labels_gt,
    const int* __restrict__ act_lens, const int* __restrict__ label_lens,
    const int* __restrict__ dec, const int* __restrict__ dec_lens,
    float* __restrict__ ends) {
  __shared__ float xall[2 * LCAP + 2];
  __shared__ float fin[2];
  const int b = blockIdx.x >> 1;
  const int hyp = blockIdx.x & 1;
  const int Tl = act_lens[b];
  const int len = hyp ? dec_lens[b] : label_lens[b];
  const int* lab = hyp ? (dec + (size_t)b * LCAP) : (labels_gt + (size_t)b * LGT);
  const int S = 2 * len + 1;
  const float* act_b = acts + (size_t)b * VV;  // acts[(t*BB + b)*VV + v]
  const int Tlm1 = Tl - 1;

  const int tid = threadIdx.x;
  const int lane = tid & 63, wv = tid >> 6;
  const int oS = 2 * ((S + 2 * NW - 1) / (2 * NW));  // even owned span
  const int Se = (S + 1) & ~1;
  const int o0 = min(wv * oS, Se);  // even
  const int o1 = min(o0 + oS, S);
  const int p0 = max(0, o0 - 62);   // even ghost bottom
  const int s0 = p0 + 2 * lane;     // blank state (even)
  const int s1 = s0 + 1;            // label state (odd)

  int e1 = 0;
  bool skip = false;
  if (s1 < S) {
    int li = s1 >> 1;
    e1 = lab[li];
    if (s1 >= 3) skip = (e1 != 0) && (e1 != lab[li - 1]);
  }

  float a0 = NEGF, a1 = NEGF;
  if (wv == 0 && lane == 0) {
    a0 = act_b[0] * L2E;
    a1 = act_b[e1] * L2E;  // S >= 3 always (len >= 1)
  }

  float gL0, gL1, gL2, gL3, gL4, gL5;  // label logits (divergent gather)
  float gB0, gB1, gB2, gB3, gB4, gB5;  // blank logits (wave-uniform)

#define PREF(GL, GB, ROW)                                  \
  {                                                        \
    const float* rp_ = act_b + (size_t)(ROW) * (BB * VV);  \
    GB = rp_[0];                                           \
    GL = rp_[e1];                                          \
  }

#define STEPK(GL, GB)                                                     \
  {                                                                       \
    float pe = shr1_negf(a1);                                             \
    /* blank (even): lse2(a0, pe) + GB */                                 \
    float m0 = fmaxf(a0, pe);                                             \
    float d0 = fminf(a0, pe) - m0;                                        \
    float n0 = m0 + __builtin_log2f(1.0f + __builtin_exp2f(d0));          \
    /* label (odd): lse3(a1, a0_old, skip?pe:NEG) + GL */                 \
    float c2 = skip ? pe : NEGF;                                          \
    float m1 = fmaxf(fmaxf(a1, a0), c2);                                  \
    float dm = __builtin_amdgcn_fmed3f(a1, a0, c2) - m1;                  \
    float dn = fminf(fminf(a1, a0), c2) - m1;                             \
    float n1 = m1 + __builtin_log2f(1.0f + __builtin_exp2f(dm) +          \
                                    __builtin_exp2f(dn));                 \
    a0 = __builtin_fmaf(GB, L2E, n0);                                     \
    a1 = __builtin_fmaf(GL, L2E, n1);                                     \
  }

#define REFRESH()                                        \
  {                                                      \
    __syncthreads();                                     \
    if (s0 >= o0 && s0 < o1) xall[s0] = a0;              \
    if (s1 >= o0 && s1 < o1) xall[s1] = a1;              \
    __syncthreads();                                     \
    if (s0 < o0) {                                       \
      a0 = xall[s0];                                     \
      a1 = (s1 < S) ? xall[s1] : NEGF;                   \
    }                                                    \
  }

  // window step: consume slot, refill same slot with row t+OFF+6 (no branches)
#define W1(OFF, GL, GB)                    \
  STEPK(GL, GB);                           \
  PREF(GL, GB, min(t + (OFF) + 6, Tlm1));

#define WROT(OB)                \
  W1(OB + 0, gL0, gB0)          \
  W1(OB + 1, gL1, gB1)          \
  W1(OB + 2, gL2, gB2)          \
  W1(OB + 3, gL3, gB3)          \
  W1(OB + 4, gL4, gB4)          \
  W1(OB + 5, gL5, gB5)

  // tail step: same rotation, with exit checks
#define T1(GL, GB)                         \
  STEPK(GL, GB);                           \
  PREF(GL, GB, min(t + 6, Tlm1));          \
  ++t;                                     \
  if (t >= Tl) break;

  // prologue: slots 0..5 = rows 1..6 (clamped)
  PREF(gL0, gB0, min(1, Tlm1));
  PREF(gL1, gB1, min(2, Tlm1));
  PREF(gL2, gB2, min(3, Tlm1));
  PREF(gL3, gB3, min(4, Tlm1));
  PREF(gL4, gB4, min(5, Tlm1));
  PREF(gL5, gB5, min(6, Tlm1));

  int t = 1;
  // main: branch-free 30-step windows; refresh once per window
  while (t + 30 <= Tl) {
    WROT(0)
    WROT(6)
    WROT(12)
    WROT(18)
    WROT(24)
    t += 30;
    REFRESH();
  }
  // tail: <= 29 steps, slot alignment preserved ((t-1)%6 == 0 on entry)
  while (t < Tl) {
    T1(gL0, gB0)
    T1(gL1, gB1)
    T1(gL2, gB2)
    T1(gL3, gB3)
    T1(gL4, gB4)
    T1(gL5, gB5)
  }
#undef T1
#undef WROT
#undef W1
#undef REFRESH
#undef STEPK
#undef PREF

  // end = logaddexp(al[2*len], al[2*len-1]) from owned states
  if (s0 >= o0 && s0 < o1 && s0 == 2 * len) fin[0] = a0;
  if (s1 >= o0 && s1 < o1 && s1 == 2 * len - 1) fin[1] = a1;
  __syncthreads();
  if (tid == 0) {
    float a = fin[0], c = fin[1];
    float m = fmaxf(a, c);
    float e = m + __builtin_log2f(__builtin_exp2f(a - m) + __builtin_exp2f(c - m));
    ends[hyp * BB + b] = e;
  }
}

// ---------------------------------------------------------------------------
// Kernel 3: out[b] = (end_hyp' - end_gt') * ln2 + 1.0  (log2-domain ends)
// ---------------------------------------------------------------------------
__global__ void final_kernel(const float* __restrict__ ends,
                             float* __restrict__ out) {
  int b = threadIdx.x;
  if (b < BB) out[b] = (ends[BB + b] - ends[b]) * LN2F + 1.0f;
}

extern "C" void kernel_launch(void* const* d_in, const int* in_sizes, int n_in,
                              void* d_out, int out_size, void* d_ws,
                              size_t ws_size, hipStream_t stream) {
  const float* acts = (const float*)d_in[0];
  const int* labels = (const int*)d_in[1];
  const int* act_lens = (const int*)d_in[2];
  const int* label_lens = (const int*)d_in[3];
  float* out = (float*)d_out;

  char* ws = (char*)d_ws;
  int* dec = (int*)ws;                                          // B*LCAP ints
  int* dec_lens = (int*)(ws + (size_t)BB * LCAP * 4);           // B ints
  float* ends = (float*)(ws + (size_t)BB * LCAP * 4 + BB * 4);  // 2*B floats

  decode_kernel<<<dim3(BB), dim3(256), 0, stream>>>(acts, act_lens, dec, dec_lens);
  ctc_kernel<<<dim3(2 * BB), dim3(1024), 0, stream>>>(
      acts, labels, act_lens, label_lens, dec, dec_lens, ends);
  final_kernel<<<dim3(1), dim3(128), 0, stream>>>(ends, out);
}

// Round 15
// 447.682 us; speedup vs baseline: 1.4635x; 1.2222x over previous
//
#include <hip/hip_runtime.h>

#define TT 1500
#define BB 96
#define VV 128
#define LGT 256
#define LCAP 512
#define NEGF (-1.0e30f)
#define L2E 1.4426950408889634f
#define LN2F 0.6931471805599453f
#define NW 11  // waves per CTC block (704 threads)

// ---------------------------------------------------------------------------
// Kernel 1: greedy decode (unchanged).
// ---------------------------------------------------------------------------
__global__ __launch_bounds__(256) void decode_kernel(
    const float* __restrict__ acts, const int* __restrict__ act_lens,
    int* __restrict__ dec, int* __restrict__ dec_lens) {
  __shared__ int preds[TT];
  __shared__ int sc[256];
  const int b = blockIdx.x;
  const int tid = threadIdx.x;
  const int Tl = act_lens[b];
  for (int t = tid; t < Tl; t += 256) {
    const float4* r4 = (const float4*)(acts + ((size_t)t * BB + b) * VV);
    float best = -3.4e38f;
    int bi = 0;
#pragma unroll
    for (int i = 0; i < VV / 4; i++) {
      float4 v = r4[i];
      if (v.x > best) { best = v.x; bi = 4 * i; }
      if (v.y > best) { best = v.y; bi = 4 * i + 1; }
      if (v.z > best) { best = v.z; bi = 4 * i + 2; }
      if (v.w > best) { best = v.w; bi = 4 * i + 3; }
    }
    preds[t] = bi;
  }
  __syncthreads();

  int pv[6];
  bool fl[6];
  int cnt = 0;
#pragma unroll
  for (int j = 0; j < 6; j++) {
    int t = tid * 6 + j;
    bool valid = t < Tl;
    int p = valid ? preds[t] : 0;
    int pr = (t == 0) ? -1 : (valid ? preds[t - 1] : -1);
    bool f = valid && (p != 0) && (p != pr);
    pv[j] = p;
    fl[j] = f;
    cnt += f;
  }
  sc[tid] = cnt;
  __syncthreads();
  for (int off = 1; off < 256; off <<= 1) {
    int v = sc[tid];
    if (tid >= off) v += sc[tid - off];
    __syncthreads();
    sc[tid] = v;
    __syncthreads();
  }
  int pos = sc[tid] - cnt;  // exclusive prefix
  int total = sc[255];
  int* db = dec + (size_t)b * LCAP;
#pragma unroll
  for (int j = 0; j < 6; j++) {
    if (fl[j]) {
      if (pos < LCAP) db[pos] = pv[j];
      pos++;
    }
  }
  if (tid == 0) {
    if (total == 0) db[0] = 0;
    dec_lens[b] = max(1, min(total, LCAP));
  }
}

// ---------------------------------------------------------------------------
// Kernel 2: CTC, r14 math (absmax 4.0) with occupancy-targeted schedule:
// 11 waves/block (704 thr), ghost 26, REFRESH every 12 steps via RAW
// s_barrier + lgkmcnt(0)-only fences (no vmcnt drain; prefetch regs stay in
// flight). 84KB dynamic LDS at launch forces 1 block/CU -> 2.75 waves/SIMD.
// Branch-free 12-step windows, 6-deep register prefetch, DPP rotate.
// ---------------------------------------------------------------------------
__device__ __forceinline__ float shr1_negf(float x) {
  // lane i <- lane i-1's x; lane 0 <- NEGF.  DPP ctrl 0x138 = wave_shr:1.
  int r = __builtin_amdgcn_update_dpp(__float_as_int(NEGF), __float_as_int(x),
                                      0x138, 0xf, 0xf, false);
  return __int_as_float(r);
}

__global__ __launch_bounds__(64 * NW, 1) void ctc_kernel(
    const float* __restrict__ acts, const int* __restrict__ labels_gt,
    const int* __restrict__ act_lens, const int* __restrict__ label_lens,
    const int* __restrict__ dec, const int* __restrict__ dec_lens,
    float* __restrict__ ends) {
  __shared__ float xall[2 * LCAP + 2];
  __shared__ float fin[2];
  const int b = blockIdx.x >> 1;
  const int hyp = blockIdx.x & 1;
  const int Tl = act_lens[b];
  const int len = hyp ? dec_lens[b] : label_lens[b];
  const int* lab = hyp ? (dec + (size_t)b * LCAP) : (labels_gt + (size_t)b * LGT);
  const int S = 2 * len + 1;
  const float* act_b = acts + (size_t)b * VV;  // acts[(t*BB + b)*VV + v]
  const int Tlm1 = Tl - 1;

  const int tid = threadIdx.x;
  const int lane = tid & 63, wv = tid >> 6;
  const int oS = 2 * ((S + 2 * NW - 1) / (2 * NW));  // even owned span (<=94)
  const int Se = (S + 1) & ~1;
  const int o0 = min(wv * oS, Se);  // even
  const int o1 = min(o0 + oS, S);
  const int p0 = max(0, o0 - 26);   // even ghost bottom (26 >= 2*12+2)
  const int s0 = p0 + 2 * lane;     // blank state (even)
  const int s1 = s0 + 1;            // label state (odd)

  int e1 = 0;
  bool skip = false;
  if (s1 < S) {
    int li = s1 >> 1;
    e1 = lab[li];
    if (s1 >= 3) skip = (e1 != 0) && (e1 != lab[li - 1]);
  }

  float a0 = NEGF, a1 = NEGF;
  if (wv == 0 && lane == 0) {
    a0 = act_b[0] * L2E;
    a1 = act_b[e1] * L2E;  // S >= 3 always (len >= 1)
  }

  float gL0, gL1, gL2, gL3, gL4, gL5;  // label logits (divergent gather)
  float gB0, gB1, gB2, gB3, gB4, gB5;  // blank logits (wave-uniform)

#define PREF(GL, GB, ROW)                                  \
  {                                                        \
    const float* rp_ = act_b + (size_t)(ROW) * (BB * VV);  \
    GB = rp_[0];                                           \
    GL = rp_[e1];                                          \
  }

#define STEPK(GL, GB)                                                     \
  {                                                                       \
    float pe = shr1_negf(a1);                                             \
    /* blank (even): lse2(a0, pe) + GB */                                 \
    float m0 = fmaxf(a0, pe);                                             \
    float d0 = fminf(a0, pe) - m0;                                        \
    float n0 = m0 + __builtin_log2f(1.0f + __builtin_exp2f(d0));          \
    /* label (odd): lse3(a1, a0_old, skip?pe:NEG) + GL */                 \
    float c2 = skip ? pe : NEGF;                                          \
    float m1 = fmaxf(fmaxf(a1, a0), c2);                                  \
    float dm = __builtin_amdgcn_fmed3f(a1, a0, c2) - m1;                  \
    float dn = fminf(fminf(a1, a0), c2) - m1;                             \
    float n1 = m1 + __builtin_log2f(1.0f + __builtin_exp2f(dm) +          \
                                    __builtin_exp2f(dn));                 \
    a0 = __builtin_fmaf(GB, L2E, n0);                                     \
    a1 = __builtin_fmaf(GL, L2E, n1);                                     \
  }

  // raw-barrier refresh: lgkmcnt-only fences; prefetch (vmcnt) stays in flight
#define REFRESH()                                        \
  {                                                      \
    asm volatile("s_waitcnt lgkmcnt(0)" ::: "memory");   \
    __builtin_amdgcn_s_barrier();                        \
    if (s0 >= o0 && s0 < o1) xall[s0] = a0;              \
    if (s1 >= o0 && s1 < o1) xall[s1] = a1;              \
    asm volatile("s_waitcnt lgkmcnt(0)" ::: "memory");   \
    __builtin_amdgcn_s_barrier();                        \
    if (s0 < o0) {                                       \
      a0 = xall[s0];                                     \
      a1 = (s1 < S) ? xall[s1] : NEGF;                   \
    }                                                    \
  }

  // window step: consume slot, refill same slot with row t+OFF+6 (no branches)
#define W1(OFF, GL, GB)                    \
  STEPK(GL, GB);                           \
  PREF(GL, GB, min(t + (OFF) + 6, Tlm1));

  // tail step: same rotation, with exit checks
#define T1(GL, GB)                         \
  STEPK(GL, GB);                           \
  PREF(GL, GB, min(t + 6, Tlm1));          \
  ++t;                                     \
  if (t >= Tl) break;

  // prologue: slots 0..5 = rows 1..6 (clamped)
  PREF(gL0, gB0, min(1, Tlm1));
  PREF(gL1, gB1, min(2, Tlm1));
  PREF(gL2, gB2, min(3, Tlm1));
  PREF(gL3, gB3, min(4, Tlm1));
  PREF(gL4, gB4, min(5, Tlm1));
  PREF(gL5, gB5, min(6, Tlm1));

  int t = 1;
  // main: branch-free 12-step windows; raw-barrier refresh each window
  while (t + 12 <= Tl) {
    W1(0, gL0, gB0)
    W1(1, gL1, gB1)
    W1(2, gL2, gB2)
    W1(3, gL3, gB3)
    W1(4, gL4, gB4)
    W1(5, gL5, gB5)
    W1(6, gL0, gB0)
    W1(7, gL1, gB1)
    W1(8, gL2, gB2)
    W1(9, gL3, gB3)
    W1(10, gL4, gB4)
    W1(11, gL5, gB5)
    t += 12;
    REFRESH();
  }
  // tail: <= 11 steps (ghost covers 13), slot alignment preserved
  while (t < Tl) {
    T1(gL0, gB0)
    T1(gL1, gB1)
    T1(gL2, gB2)
    T1(gL3, gB3)
    T1(gL4, gB4)
    T1(gL5, gB5)
  }
#undef T1
#undef W1
#undef REFRESH
#undef STEPK
#undef PREF

  // end = logaddexp(al[2*len], al[2*len-1]) from owned states
  __syncthreads();
  if (s0 >= o0 && s0 < o1 && s0 == 2 * len) fin[0] = a0;
  if (s1 >= o0 && s1 < o1 && s1 == 2 * len - 1) fin[1] = a1;
  __syncthreads();
  if (tid == 0) {
    float a = fin[0], c = fin[1];
    float m = fmaxf(a, c);
    float e = m + __builtin_log2f(__builtin_exp2f(a - m) + __builtin_exp2f(c - m));
    ends[hyp * BB + b] = e;
  }
}

// ---------------------------------------------------------------------------
// Kernel 3: out[b] = (end_hyp' - end_gt') * ln2 + 1.0  (log2-domain ends)
// ---------------------------------------------------------------------------
__global__ void final_kernel(const float* __restrict__ ends,
                             float* __restrict__ out) {
  int b = threadIdx.x;
  if (b < BB) out[b] = (ends[BB + b] - ends[b]) * LN2F + 1.0f;
}

extern "C" void kernel_launch(void* const* d_in, const int* in_sizes, int n_in,
                              void* d_out, int out_size, void* d_ws,
                              size_t ws_size, hipStream_t stream) {
  const float* acts = (const float*)d_in[0];
  const int* labels = (const int*)d_in[1];
  const int* act_lens = (const int*)d_in[2];
  const int* label_lens = (const int*)d_in[3];
  float* out = (float*)d_out;

  char* ws = (char*)d_ws;
  int* dec = (int*)ws;                                          // B*LCAP ints
  int* dec_lens = (int*)(ws + (size_t)BB * LCAP * 4);           // B ints
  float* ends = (float*)(ws + (size_t)BB * LCAP * 4 + BB * 4);  // 2*B floats

  decode_kernel<<<dim3(BB), dim3(256), 0, stream>>>(acts, act_lens, dec, dec_lens);
  // 84KB dynamic LDS: forces 1 block/CU (88KB total; 2x > 160KB) so the
  // 192 blocks spread over 192 CUs -> max 11 waves / 4 SIMDs per CU.
  ctc_kernel<<<dim3(2 * BB), dim3(64 * NW), 84 * 1024, stream>>>(
      acts, labels, act_lens, label_lens, dec, dec_lens, ends);
  final_kernel<<<dim3(1), dim3(128), 0, stream>>>(ends, out);
}